// Round 5
// baseline (599.563 us; speedup 1.0000x reference)
//
#include <hip/hip_runtime.h>

#define M_SZ 32768
#define N_SZ 4096
#define DEPTHS 4

typedef __attribute__((ext_vector_type(8))) short bh8;   // 8 bf16 MFMA frag
typedef __attribute__((ext_vector_type(4))) float f4;    // MFMA accumulator
typedef unsigned short u16;
typedef unsigned int u32;

#define SBAR() __builtin_amdgcn_s_barrier()
#define FENCE() asm volatile("" ::: "memory")
#define WAITV(n) asm volatile("s_waitcnt vmcnt(" #n ")" ::: "memory")
#define WAITVL(n) asm volatile("s_waitcnt vmcnt(" #n ") lgkmcnt(0)" ::: "memory")

__device__ __forceinline__ u16 f2bf(float f) {
  u32 u = __float_as_uint(f);
  u = (u + 0x7FFFu + ((u >> 16) & 1u)) >> 16;  // RNE
  return (u16)u;
}

__device__ __forceinline__ float fast_tanh(float x) {
  float ax = __builtin_fabsf(x);
  float e = __builtin_exp2f(ax * 2.8853900817779268f);  // e^(2|x|)
  float r = 1.0f - 2.0f * __builtin_amdgcn_rcpf(e + 1.0f);
  return __builtin_copysignf(r, x);
}

__device__ __forceinline__ void async16(const void* g, void* l) {
  __builtin_amdgcn_global_load_lds((const __attribute__((address_space(1))) u32*)g,
                                   (__attribute__((address_space(3))) u32*)l, 16, 0, 0);
}

// ---------------------------------------------------------------------------
// t0: sT[c][n] = self_act[n][c]  (64x64 tiles via LDS, both sides coalesced)
// ---------------------------------------------------------------------------
__global__ void t0_kernel(const float* __restrict__ in, float* __restrict__ sT) {
  __shared__ float tile[64 * 68];
  const int t = threadIdx.x;
  const int n0 = blockIdx.x * 64, c0 = blockIdx.y * 64;
#pragma unroll
  for (int j = 0; j < 4; ++j) {
    int row = j * 16 + (t >> 4), c4 = t & 15;
    float4 v = *(const float4*)(in + (size_t)(n0 + row) * 128 + c0 + c4 * 4);
    tile[row * 68 + c4 * 4 + 0] = v.x;
    tile[row * 68 + c4 * 4 + 1] = v.y;
    tile[row * 68 + c4 * 4 + 2] = v.z;
    tile[row * 68 + c4 * 4 + 3] = v.w;
  }
  __syncthreads();
#pragma unroll
  for (int j = 0; j < 4; ++j) {
    int cc = j * 16 + (t >> 4), r4 = t & 15;
    float4 v;
    v.x = tile[(r4 * 4 + 0) * 68 + cc];
    v.y = tile[(r4 * 4 + 1) * 68 + cc];
    v.z = tile[(r4 * 4 + 2) * 68 + cc];
    v.w = tile[(r4 * 4 + 3) * 68 + cc];
    *(float4*)(sT + (size_t)(c0 + cc) * 4096 + n0 + r4 * 4) = v;
  }
}

// ---------------------------------------------------------------------------
// k1: y_d[i][n] = sum_k sT[k][n] * Wd[i][k]  (write transposed bf16)
// ---------------------------------------------------------------------------
__global__ void k1_kernel(const float* __restrict__ sT, const float* __restrict__ Wd,
                          u16* __restrict__ Ytd, u32* __restrict__ cnt) {
  __shared__ float wlds[16 * 132];
  const int t = threadIdx.x;
  if (blockIdx.x == 0 && blockIdx.y == 0 && t < 64) cnt[t] = 0;
  const int n0 = blockIdx.x * 64, i0 = blockIdx.y * 16;
  const int iq = t & 15, ng = t >> 4;
  const int n = n0 + ng * 4;
#pragma unroll
  for (int j = 0; j < 2; ++j) {
    int li = j * 256 + t;
    int row = li >> 5, c4 = li & 31;
    float4 v = *(const float4*)(Wd + (i0 + row) * 128 + c4 * 4);
    *(float4*)(wlds + row * 132 + c4 * 4) = v;
  }
  __syncthreads();
  float acc[4] = {0.f, 0.f, 0.f, 0.f};
#pragma unroll 4
  for (int k4 = 0; k4 < 32; ++k4) {
    float4 wv = *(const float4*)(wlds + iq * 132 + k4 * 4);
#pragma unroll
    for (int j = 0; j < 4; ++j) {
      float4 sv = *(const float4*)(sT + (size_t)(k4 * 4 + j) * 4096 + n);
      float w = (j == 0) ? wv.x : (j == 1) ? wv.y : (j == 2) ? wv.z : wv.w;
      acc[0] = fmaf(w, sv.x, acc[0]);
      acc[1] = fmaf(w, sv.y, acc[1]);
      acc[2] = fmaf(w, sv.z, acc[2]);
      acc[3] = fmaf(w, sv.w, acc[3]);
    }
  }
  union { ushort4 v; u16 u[4]; } o;
#pragma unroll
  for (int j = 0; j < 4; ++j) o.u[j] = f2bf(acc[j]);
  *(ushort4*)(Ytd + (size_t)(i0 + iq) * 4096 + n) = o.v;
}

// ---------------------------------------------------------------------------
// k2: z = SK @ y_d, split-K 4 + deterministic last-block finisher.
// grid (64 nb, 4 c), 512 thr. tile 64n x 128i, K-chunk 1024, K-step 64.
// Finisher: fixed-order c-sum + bias + tanh -> s_out AND sT (LDS transpose).
// ---------------------------------------------------------------------------
__global__ __launch_bounds__(512, 2) void k2_kernel(
    const float* __restrict__ SK, const u16* __restrict__ Ytd,
    float* __restrict__ Zp, u32* __restrict__ cnt,
    const float* __restrict__ s_src, float* __restrict__ s_out,
    float* __restrict__ sT, const float* __restrict__ bd) {
  __shared__ char smem[8192 + 2 * 16384];
  __shared__ u32 lastFlag;
  char* sA = smem;
  char* sB0 = smem + 8192;
  char* sB1 = smem + 8192 + 16384;
  const int t = threadIdx.x, lane = t & 63, wid = t >> 6;
  const int nb = blockIdx.x, c = blockIdx.y;
  const int n0 = nb * 64;
  const int kbz = c * 1024;
  const int wr = wid >> 1, wc = wid & 1;
  const int l15 = lane & 15, l4 = lane >> 4;

  const int arow = t >> 3, kseg8 = t & 7;
  const float4* agz = (const float4*)(SK + (size_t)(n0 + arow) * 4096 + kbz + kseg8 * 8);
  const int awoff = arow * 128 + ((kseg8 ^ (arow & 7)) << 4);

  int bcol[2], bgq[2], bldst[2];
#pragma unroll
  for (int j = 0; j < 2; ++j) {
    int G = j * 512 + t;
    bcol[j] = G >> 3;
    bgq[j] = (G & 7) ^ (bcol[j] & 7);
    bldst[j] = G * 16;
  }

  int aro, bro[4];
  {
    int row = wr * 16 + l15;
    aro = row * 128 + ((l4 ^ (row & 7)) << 4);
  }
#pragma unroll
  for (int n2 = 0; n2 < 4; ++n2) {
    int col = wc * 64 + n2 * 16 + l15;
    bro[n2] = col * 128 + ((l4 ^ (col & 7)) << 4);
  }

  f4 acc[4];
#pragma unroll
  for (int j = 0; j < 4; ++j) acc[j] = (f4){0.f, 0.f, 0.f, 0.f};

  float4 va0 = agz[0], va1 = agz[1];
  FENCE();
  async16(Ytd + (size_t)bcol[0] * 4096 + kbz + bgq[0] * 8, sB0 + bldst[0]);
  async16(Ytd + (size_t)bcol[1] * 4096 + kbz + bgq[1] * 8, sB0 + bldst[1]);
  FENCE();
  char* sBc = sB0;
  char* sBn = sB1;
  for (int k = 0; k < 15; ++k) {
    SBAR(); FENCE();
    WAITV(2);
    union { bh8 v; u16 u[8]; } p;
    p.u[0] = f2bf(va0.x); p.u[1] = f2bf(va0.y); p.u[2] = f2bf(va0.z); p.u[3] = f2bf(va0.w);
    p.u[4] = f2bf(va1.x); p.u[5] = f2bf(va1.y); p.u[6] = f2bf(va1.z); p.u[7] = f2bf(va1.w);
    *(bh8*)(sA + awoff) = p.v;
    FENCE();
    va0 = agz[(k + 1) * 16]; va1 = agz[(k + 1) * 16 + 1];
    FENCE();
    WAITVL(2);
    SBAR(); FENCE();
    async16(Ytd + (size_t)bcol[0] * 4096 + kbz + bgq[0] * 8 + (k + 1) * 64, sBn + bldst[0]);
    async16(Ytd + (size_t)bcol[1] * 4096 + kbz + bgq[1] * 8 + (k + 1) * 64, sBn + bldst[1]);
    FENCE();
#pragma unroll
    for (int kk = 0; kk < 2; ++kk) {
      bh8 a = *(const bh8*)(sA + (aro ^ (kk << 6)));
#pragma unroll
      for (int n2 = 0; n2 < 4; ++n2) {
        bh8 bb = *(const bh8*)(sBc + (bro[n2] ^ (kk << 6)));
        acc[n2] = __builtin_amdgcn_mfma_f32_16x16x32_bf16(a, bb, acc[n2], 0, 0, 0);
      }
    }
    char* tp = sBc; sBc = sBn; sBn = tp;
  }
  SBAR(); FENCE();
  WAITV(2);
  {
    union { bh8 v; u16 u[8]; } p;
    p.u[0] = f2bf(va0.x); p.u[1] = f2bf(va0.y); p.u[2] = f2bf(va0.z); p.u[3] = f2bf(va0.w);
    p.u[4] = f2bf(va1.x); p.u[5] = f2bf(va1.y); p.u[6] = f2bf(va1.z); p.u[7] = f2bf(va1.w);
    *(bh8*)(sA + awoff) = p.v;
  }
  WAITVL(0);
  SBAR(); FENCE();
#pragma unroll
  for (int kk = 0; kk < 2; ++kk) {
    bh8 a = *(const bh8*)(sA + (aro ^ (kk << 6)));
#pragma unroll
    for (int n2 = 0; n2 < 4; ++n2) {
      bh8 bb = *(const bh8*)(sBc + (bro[n2] ^ (kk << 6)));
      acc[n2] = __builtin_amdgcn_mfma_f32_16x16x32_bf16(a, bb, acc[n2], 0, 0, 0);
    }
  }

  float* Z = Zp + (size_t)c * (N_SZ * 128) + (size_t)n0 * 128;
#pragma unroll
  for (int n2 = 0; n2 < 4; ++n2)
#pragma unroll
    for (int q = 0; q < 4; ++q) {
      int r = wr * 16 + l4 * 4 + q;
      int cc = wc * 64 + n2 * 16 + l15;
      Z[r * 128 + cc] = acc[n2][q];
    }

  __threadfence();
  __syncthreads();
  if (t == 0) lastFlag = (atomicAdd(&cnt[nb], 1) == 3) ? 1u : 0u;
  __syncthreads();
  if (lastFlag) {
    __threadfence();
    float* ftile = (float*)smem;  // [64][130] f32
    for (int idx = t; idx < 64 * 128; idx += 512) {
      int r = idx >> 7, ccol = idx & 127;
      float v = bd[ccol];
#pragma unroll
      for (int cc = 0; cc < 4; ++cc)
        v += Zp[(size_t)cc * (N_SZ * 128) + (size_t)(n0 + r) * 128 + ccol];
      float res = s_src[(size_t)(n0 + r) * 128 + ccol] + fast_tanh(v);
      s_out[(size_t)(n0 + r) * 128 + ccol] = res;
      ftile[r * 130 + ccol] = res;
    }
    __syncthreads();
    for (int idx = t; idx < 64 * 128; idx += 512) {
      int rr = idx & 63, cc = idx >> 6;
      sT[(size_t)cc * 4096 + n0 + rr] = ftile[rr * 130 + cc];
    }
  }
}

// ---------------------------------------------------------------------------
// pB v3: out = act + sum_d tanh(kern @ y_d + b_d). SINGLE pass over 512MB A.
// grid 256 (1 block/CU), 512 thr (8 waves 2x4). Tile 128r x 512tc (4 depths).
// A staged as RAW F32 via global_load_lds (cvt to bf16 at consume).
// 3-deep multibuffer (LDS 144KB), one barrier/iter, counted vmcnt(6):
// per thread per iter 2 A + 4 B async16; depth-2 prefetch in flight.
// K-step 32, 128 iters. VGPR ~190 -> launch_bounds(512,2), no spill.
// ---------------------------------------------------------------------------
__global__ __launch_bounds__(512, 2) void pB_kernel(
    const float* __restrict__ A, const u16* __restrict__ Yt,
    const float* __restrict__ act, const float* __restrict__ bias,
    float* __restrict__ outA) {
  __shared__ char smem[3 * (16384 + 32768)];  // 3 slabs: [A 16K | B 32K]
  const int t = threadIdx.x, lane = t & 63, wid = t >> 6;
  const int wr = wid >> 2, wc = wid & 3;
  const int m0 = blockIdx.x * 128;
  const int l15 = lane & 15, l4 = lane >> 4;

  // A staging: [128 r][8 seg of 4 f32] per slab; granule G = j*512+t
  const float* asrc[2];
  int aldst[2];
#pragma unroll
  for (int j = 0; j < 2; ++j) {
    int G = j * 512 + t;
    int row = G >> 3, p = G & 7;
    int seg = p ^ (row & 7);
    asrc[j] = A + (size_t)(m0 + row) * 4096 + seg * 4;
    aldst[j] = G * 16;
  }
  // B staging: [512 tc][4 seg of 8 bf16]; granule G2 = j*512+t
  const u16* bsrc[4];
  int bldst[4];
#pragma unroll
  for (int j = 0; j < 4; ++j) {
    int G2 = j * 512 + t;
    int col = G2 >> 2, p = G2 & 3;
    int seg = p ^ ((col >> 1) & 3);
    bsrc[j] = Yt + (size_t)col * 4096 + seg * 8;
    bldst[j] = G2 * 16;
  }

  // consume offsets
  int arby[4], as0[4], as1[4];
#pragma unroll
  for (int mf = 0; mf < 4; ++mf) {
    int row = wr * 64 + mf * 16 + l15;
    arby[mf] = row * 128;
    as0[mf] = ((l4 * 2) ^ (row & 7)) * 16;
    as1[mf] = ((l4 * 2 + 1) ^ (row & 7)) * 16;
  }
  int bro[4][2];
#pragma unroll
  for (int d = 0; d < 4; ++d)
#pragma unroll
    for (int n2 = 0; n2 < 2; ++n2) {
      int tc = d * 128 + wc * 32 + n2 * 16 + l15;
      bro[d][n2] = tc * 64 + ((l4 ^ ((tc >> 1) & 3)) << 4);
    }

  f4 acc[4][4][2];
#pragma unroll
  for (int i = 0; i < 4; ++i)
#pragma unroll
    for (int j = 0; j < 4; ++j)
#pragma unroll
      for (int k = 0; k < 2; ++k) acc[i][j][k] = (f4){0.f, 0.f, 0.f, 0.f};

  // prologue: issue iters 0 and 1 (6 loads each, FIFO order A,A,B,B,B,B)
#pragma unroll
  for (int pre = 0; pre < 2; ++pre) {
    char* Ab = smem + pre * 49152;
    char* Bb = Ab + 16384;
    async16(asrc[0] + pre * 32, Ab + aldst[0]);
    async16(asrc[1] + pre * 32, Ab + aldst[1]);
#pragma unroll
    for (int j = 0; j < 4; ++j) async16(bsrc[j] + pre * 32, Bb + bldst[j]);
  }
  FENCE();

#define PB_CONSUME(Ab, Bb)                                                        \
  {                                                                               \
    bh8 af[4];                                                                    \
    _Pragma("unroll") for (int mf = 0; mf < 4; ++mf) {                            \
      f4 x = *(const f4*)((Ab) + arby[mf] + as0[mf]);                             \
      f4 y = *(const f4*)((Ab) + arby[mf] + as1[mf]);                             \
      union { bh8 v; u16 u[8]; } pk;                                              \
      pk.u[0] = f2bf(x[0]); pk.u[1] = f2bf(x[1]);                                 \
      pk.u[2] = f2bf(x[2]); pk.u[3] = f2bf(x[3]);                                 \
      pk.u[4] = f2bf(y[0]); pk.u[5] = f2bf(y[1]);                                 \
      pk.u[6] = f2bf(y[2]); pk.u[7] = f2bf(y[3]);                                 \
      af[mf] = pk.v;                                                              \
    }                                                                             \
    _Pragma("unroll") for (int d = 0; d < 4; ++d)                                 \
      _Pragma("unroll") for (int n2 = 0; n2 < 2; ++n2) {                          \
        bh8 b = *(const bh8*)((Bb) + bro[d][n2]);                                 \
        _Pragma("unroll") for (int mf = 0; mf < 4; ++mf)                          \
          acc[mf][d][n2] =                                                        \
              __builtin_amdgcn_mfma_f32_16x16x32_bf16(af[mf], b, acc[mf][d][n2], \
                                                      0, 0, 0);                   \
      }                                                                           \
  }

#pragma unroll 1
  for (int k = 0; k < 126; ++k) {
    WAITV(6);
    SBAR(); FENCE();
    char* Ab = smem + (k % 3) * 49152;
    char* Bb = Ab + 16384;
    char* An = smem + ((k + 2) % 3) * 49152;
    char* Bn = An + 16384;
    async16(asrc[0] + (k + 2) * 32, An + aldst[0]);
    async16(asrc[1] + (k + 2) * 32, An + aldst[1]);
#pragma unroll
    for (int j = 0; j < 4; ++j) async16(bsrc[j] + (k + 2) * 32, Bn + bldst[j]);
    FENCE();
    PB_CONSUME(Ab, Bb)
  }
  // k = 126 (loads already issued; iter 127's still in flight)
  WAITV(6);
  SBAR(); FENCE();
  PB_CONSUME(smem + 0 * 49152, smem + 0 * 49152 + 16384)
  // k = 127
  WAITV(0);
  SBAR(); FENCE();
  PB_CONSUME(smem + 1 * 49152, smem + 1 * 49152 + 16384)

  float bsv[4][2];
#pragma unroll
  for (int d = 0; d < 4; ++d) {
    bsv[d][0] = bias[d * 128 + wc * 32 + l15];
    bsv[d][1] = bias[d * 128 + wc * 32 + 16 + l15];
  }
#pragma unroll
  for (int mf = 0; mf < 4; ++mf)
#pragma unroll
    for (int q = 0; q < 4; ++q) {
      int r = m0 + wr * 64 + mf * 16 + l4 * 4 + q;
      int c = wc * 32 + l15;
      float s0 = 0.f, s1 = 0.f;
#pragma unroll
      for (int d = 0; d < 4; ++d) {
        s0 += fast_tanh(acc[mf][d][0][q] + bsv[d][0]);
        s1 += fast_tanh(acc[mf][d][1][q] + bsv[d][1]);
      }
      size_t o0 = (size_t)r * 128 + c;
      outA[o0] = act[o0] + s0;
      outA[o0 + 16] = act[o0 + 16] + s1;
    }
}

// ---------------------------------------------------------------------------
extern "C" void kernel_launch(void* const* d_in, const int* in_sizes, int n_in,
                              void* d_out, int out_size, void* d_ws, size_t ws_size,
                              hipStream_t stream) {
  const float* act = (const float*)d_in[0];
  const float* self_act = (const float*)d_in[1];
  const float* kern = (const float*)d_in[2];
  const float* self_kern = (const float*)d_in[3];
  const float* weights = (const float*)d_in[4];
  const float* bias = (const float*)d_in[5];
  float* out = (float*)d_out;
  float* s_out = out + (size_t)M_SZ * 128;

  char* ws = (char*)d_ws;
  u16* Yt = (u16*)ws;                          // [512][4096] bf16, 4 MB
  float* Zp = (float*)(ws + (4u << 20));       // [4][4096][128] f32, 8 MB
  u32* counters = (u32*)(ws + (12u << 20));    // [4][64]
  float* sT = (float*)(ws + (16u << 20));      // [128][4096] f32, 2 MB

  t0_kernel<<<dim3(64, 2), 256, 0, stream>>>(self_act, sT);
  for (int d = 0; d < DEPTHS; ++d) {
    const float* s_src = (d == 0) ? self_act : s_out;
    k1_kernel<<<dim3(64, 8), 256, 0, stream>>>(sT, weights + d * 16384,
                                               Yt + (size_t)d * 128 * 4096,
                                               counters + d * 64);
    k2_kernel<<<dim3(64, 4), 512, 0, stream>>>(self_kern, Yt + (size_t)d * 128 * 4096,
                                               Zp, counters + d * 64, s_src, s_out, sT,
                                               bias + d * 128);
  }
  pB_kernel<<<256, 512, 0, stream>>>(kern, Yt, act, bias, out);
}